// Round 4
// baseline (345.257 us; speedup 1.0000x reference)
//
#include <hip/hip_runtime.h>
#include <hip/hip_fp16.h>
#include <math.h>

// Problem constants (from reference): N=100000, H=256, E=3200000, OUT=2
#define HDIM 256
#define NEG_SLOPE 0.2f

// R7: k_proc is an HBM-starved stream (dur == FETCH/200GB/s in both R2 and
// R3, invariant to gather ILP). Cause: stream loads are consumed immediately
// (gather addrs depend on them), so outstanding stream bytes ~0 most of the
// time. Fix: phase-decoupled chunks of 4096 records — issue all 4 uint4
// stream loads/thread back-to-back, then all 16 gathers, then LDS atomics.

#define BSHIFT 7
#define BMASK 127
#define MAXBKT 1024   // supports n <= 131072
#define EPB 6144      // edges per k_bin block (multiple of 1024)

__device__ __forceinline__ float leaky(float v) {
    return v >= 0.0f ? v : NEG_SLOPE * v;
}

// order-preserving float<->uint encoding for atomicMax over signed floats
__device__ __forceinline__ unsigned enc_f32(float f) {
    unsigned b = __float_as_uint(f);
    return b ^ ((b >> 31) ? 0xFFFFFFFFu : 0x80000000u);
}
__device__ __forceinline__ float dec_f32(unsigned u) {
    u ^= ((u >> 31) ? 0x80000000u : 0xFFFFFFFFu);
    return __uint_as_float(u);
}

// ---------------- Kernel 1: per-node z, el, er --------------------------------
__global__ void k_node(const float* __restrict__ input,
                       const float* __restrict__ W,
                       const float* __restrict__ attn_l,
                       const float* __restrict__ attn_r,
                       float4* __restrict__ nodeinfo,  // (el, er, z0, z1)
                       float* __restrict__ el_arr,
                       float* __restrict__ er_arr,
                       int n)
{
    int node = blockIdx.x * 4 + (threadIdx.x >> 6);
    int lane = threadIdx.x & 63;
    if (node >= n) return;

    const float4* inrow = (const float4*)(input + (size_t)node * HDIM);
    float4 v = inrow[lane];
    const float4* Wv = (const float4*)W;
    float4 w0 = Wv[2 * lane];
    float4 w1 = Wv[2 * lane + 1];
    float s0 = v.x * w0.x + v.y * w0.z + v.z * w1.x + v.w * w1.z;
    float s1 = v.x * w0.y + v.y * w0.w + v.z * w1.y + v.w * w1.w;

    #pragma unroll
    for (int off = 32; off > 0; off >>= 1) {
        s0 += __shfl_xor(s0, off);
        s1 += __shfl_xor(s1, off);
    }

    if (lane == 0) {
        float el = s0 * attn_l[0] + s1 * attn_l[1];
        float er = s0 * attn_r[0] + s1 * attn_r[1];
        nodeinfo[node] = make_float4(el, er, s0, s1);
        el_arr[node] = el;
        er_arr[node] = er;
    }
}

// ---------------- Kernel 2: global max of el ----------------------------------
__global__ void k_maxel(const float* __restrict__ el, unsigned* __restrict__ M_enc, int n)
{
    float m = -1e30f;
    for (int i = blockIdx.x * blockDim.x + threadIdx.x; i < n;
         i += gridDim.x * blockDim.x)
        m = fmaxf(m, el[i]);
    #pragma unroll
    for (int off = 32; off > 0; off >>= 1)
        m = fmaxf(m, __shfl_xor(m, off));
    __shared__ float s[4];
    int lane = threadIdx.x & 63, w = threadIdx.x >> 6;
    if (lane == 0) s[w] = m;
    __syncthreads();
    if (threadIdx.x == 0) {
        float mm = fmaxf(fmaxf(s[0], s[1]), fmaxf(s[2], s[3]));
        atomicMax(M_enc, enc_f32(mm));   // M_enc pre-zeroed; enc(0)=0 acts as -inf
    }
}

// ---------------- Kernel 3a: bin edges by dst bucket ---------------------------
// Record: (src << 7) | (dst & 127) fits u32 for n <= 131072.
__global__ __launch_bounds__(256, 4)
void k_bin(const int* __restrict__ src,
           const int* __restrict__ dst,
           unsigned* __restrict__ cursor,    // [nbkt], pre-zeroed
           unsigned* __restrict__ edgebuf,   // [nbkt*cap]
           const float4* __restrict__ nodeinfo,
           const float* __restrict__ er_arr,
           const unsigned* __restrict__ M_enc,
           unsigned* __restrict__ num,       // overflow fallback (pre-zeroed)
           float* __restrict__ denom,        // overflow fallback (pre-zeroed)
           int e, int nbkt, int cap)
{
    __shared__ unsigned h1[MAXBKT];        // counts -> block's base per bucket
    __shared__ unsigned h2[MAXBKT];        // local ranks
    __shared__ unsigned recs[EPB];         // packed records
    __shared__ unsigned short bkt[EPB];    // bucket id per record

    for (int t = threadIdx.x; t < nbkt; t += blockDim.x) { h1[t] = 0u; h2[t] = 0u; }
    __syncthreads();

    int lo = blockIdx.x * EPB;
    int cnt = min(EPB, e - lo);

    // pass 1: coalesced load, pack record, LDS histogram
    if (cnt == EPB) {
        const int4* s4 = (const int4*)(src + lo);
        const int4* d4 = (const int4*)(dst + lo);
        #pragma unroll
        for (int k = 0; k < EPB / 1024; ++k) {
            int i4 = (int)threadIdx.x + k * 256;
            int4 sv = s4[i4];
            int4 dv = d4[i4];
            int i = 4 * i4;
            recs[i + 0] = ((unsigned)sv.x << BSHIFT) | ((unsigned)dv.x & BMASK);
            recs[i + 1] = ((unsigned)sv.y << BSHIFT) | ((unsigned)dv.y & BMASK);
            recs[i + 2] = ((unsigned)sv.z << BSHIFT) | ((unsigned)dv.z & BMASK);
            recs[i + 3] = ((unsigned)sv.w << BSHIFT) | ((unsigned)dv.w & BMASK);
            bkt[i + 0] = (unsigned short)((unsigned)dv.x >> BSHIFT);
            bkt[i + 1] = (unsigned short)((unsigned)dv.y >> BSHIFT);
            bkt[i + 2] = (unsigned short)((unsigned)dv.z >> BSHIFT);
            bkt[i + 3] = (unsigned short)((unsigned)dv.w >> BSHIFT);
            atomicAdd(&h1[(unsigned)dv.x >> BSHIFT], 1u);
            atomicAdd(&h1[(unsigned)dv.y >> BSHIFT], 1u);
            atomicAdd(&h1[(unsigned)dv.z >> BSHIFT], 1u);
            atomicAdd(&h1[(unsigned)dv.w >> BSHIFT], 1u);
        }
    } else {
        for (int i = threadIdx.x; i < cnt; i += blockDim.x) {
            int s = src[lo + i];
            int d = dst[lo + i];
            recs[i] = ((unsigned)s << BSHIFT) | ((unsigned)d & BMASK);
            bkt[i] = (unsigned short)((unsigned)d >> BSHIFT);
            atomicAdd(&h1[(unsigned)d >> BSHIFT], 1u);
        }
    }
    __syncthreads();

    // reserve contiguous per-bucket ranges (the only global atomics)
    for (int t = threadIdx.x; t < nbkt; t += blockDim.x) {
        unsigned c = h1[t];
        h1[t] = c ? atomicAdd(&cursor[t], c) : 0u;
    }
    __syncthreads();

    // pass 2: scatter packed records from LDS
    for (int i = threadIdx.x; i < cnt; i += blockDim.x) {
        int b = (int)bkt[i];
        unsigned rec = recs[i];
        unsigned r = h1[b] + atomicAdd(&h2[b], 1u);
        if (r < (unsigned)cap) {
            edgebuf[(size_t)b * cap + r] = rec;
        } else {
            // statistically-never overflow: old direct global-atomic path
            int s = (int)(rec >> BSHIFT);
            int d = (b << BSHIFT) | (int)(rec & BMASK);
            float Mel = dec_f32(*M_enc);
            float4 ns = nodeinfo[s];
            float erd = er_arr[d];
            float ex = __expf(leaky(ns.x + erd) - leaky(Mel + erd));
            __half2 h = __floats2half2_rn(ex * ns.z, ex * ns.w);
            unsigned hv = *(unsigned*)&h;
            unsigned* np = num + d;
            asm volatile("global_atomic_pk_add_f16 %0, %1, off"
                         :: "v"(np), "v"(hv) : "memory");
            float* dp = denom + d;
            asm volatile("global_atomic_add_f32 %0, %1, off"
                         :: "v"(dp), "v"(ex) : "memory");
        }
    }
}

// ---------------- Kernel 3b: per-bucket LDS accumulate + fused gate ------------
// Phase-decoupled chunks: 4 independent uint4 stream loads/thread issued
// before any dependent use, then 16 gathers, then LDS-atomic accumulation.
__global__ __launch_bounds__(256, 4)
void k_proc(const unsigned* __restrict__ cursor,
            const unsigned* __restrict__ edgebuf,
            const float4* __restrict__ nodeinfo,
            const float* __restrict__ er_arr,
            const unsigned* __restrict__ M_enc,
            const unsigned* __restrict__ num,    // overflow partials
            const float* __restrict__ denom,     // overflow partials
            const float* __restrict__ x,
            const float* __restrict__ bias,
            float* __restrict__ g,
            int n, int cap)
{
    __shared__ float sD[128], s0[128], s1[128], ser[128];
    int b = blockIdx.x;
    int dbase = b << BSHIFT;
    int t = threadIdx.x;
    if (t < 128) {
        sD[t] = 0.f; s0[t] = 0.f; s1[t] = 0.f;
        int d = dbase + t;
        ser[t] = (d < n) ? er_arr[d] : 0.f;
    }
    __syncthreads();

    float Mel = dec_f32(*M_enc);
    unsigned cnt = cursor[b];
    if (cnt > (unsigned)cap) cnt = (unsigned)cap;
    const unsigned* buf = edgebuf + (size_t)b * cap;   // 16B aligned (cap % 4 == 0)
    const uint4* buf4 = (const uint4*)buf;
    unsigned nvec = cnt >> 2;

    #define PROC1(rec, ns) do {                                        \
        int dl_ = (int)((rec) & BMASK);                                \
        float erd_ = ser[dl_];                                         \
        float ex_ = __expf(leaky((ns).x + erd_) - leaky(Mel + erd_));  \
        atomicAdd(&sD[dl_], ex_);                                      \
        atomicAdd(&s0[dl_], ex_ * (ns).z);                             \
        atomicAdd(&s1[dl_], ex_ * (ns).w);                             \
    } while (0)

    // chunk = 1024 vec4 = 4096 records; typical bucket (~4092) is one chunk.
    for (unsigned base4 = 0; base4 < nvec; base4 += 1024u) {
        unsigned i0 = base4 + (unsigned)t;
        unsigned i1 = i0 + 256u, i2 = i0 + 512u, i3 = i0 + 768u;
        bool v0 = i0 < nvec, v1 = i1 < nvec, v2 = i2 < nvec, v3 = i3 < nvec;
        // phase 1: all stream loads issued back-to-back (independent)
        uint4 r0 = v0 ? buf4[i0] : make_uint4(0u, 0u, 0u, 0u);
        uint4 r1 = v1 ? buf4[i1] : make_uint4(0u, 0u, 0u, 0u);
        uint4 r2 = v2 ? buf4[i2] : make_uint4(0u, 0u, 0u, 0u);
        uint4 r3 = v3 ? buf4[i3] : make_uint4(0u, 0u, 0u, 0u);
        // phase 2: all gathers (masked lanes gather nodeinfo[0], harmless)
        float4 nf0x = nodeinfo[r0.x >> BSHIFT], nf0y = nodeinfo[r0.y >> BSHIFT];
        float4 nf0z = nodeinfo[r0.z >> BSHIFT], nf0w = nodeinfo[r0.w >> BSHIFT];
        float4 nf1x = nodeinfo[r1.x >> BSHIFT], nf1y = nodeinfo[r1.y >> BSHIFT];
        float4 nf1z = nodeinfo[r1.z >> BSHIFT], nf1w = nodeinfo[r1.w >> BSHIFT];
        float4 nf2x = nodeinfo[r2.x >> BSHIFT], nf2y = nodeinfo[r2.y >> BSHIFT];
        float4 nf2z = nodeinfo[r2.z >> BSHIFT], nf2w = nodeinfo[r2.w >> BSHIFT];
        float4 nf3x = nodeinfo[r3.x >> BSHIFT], nf3y = nodeinfo[r3.y >> BSHIFT];
        float4 nf3z = nodeinfo[r3.z >> BSHIFT], nf3w = nodeinfo[r3.w >> BSHIFT];
        // phase 3: accumulate
        if (v0) { PROC1(r0.x, nf0x); PROC1(r0.y, nf0y); PROC1(r0.z, nf0z); PROC1(r0.w, nf0w); }
        if (v1) { PROC1(r1.x, nf1x); PROC1(r1.y, nf1y); PROC1(r1.z, nf1z); PROC1(r1.w, nf1w); }
        if (v2) { PROC1(r2.x, nf2x); PROC1(r2.y, nf2y); PROC1(r2.z, nf2z); PROC1(r2.w, nf2w); }
        if (v3) { PROC1(r3.x, nf3x); PROC1(r3.y, nf3y); PROC1(r3.z, nf3z); PROC1(r3.w, nf3w); }
    }
    // tail: < 4 records
    for (unsigned i = (nvec << 2) + (unsigned)t; i < cnt; i += blockDim.x) {
        unsigned rec = buf[i];
        float4 ns = nodeinfo[rec >> BSHIFT];
        PROC1(rec, ns);
    }
    #undef PROC1
    __syncthreads();

    if (t < 128) {
        int d = dbase + t;
        if (d < n) {
            float D = sD[t] + denom[d];   // merge (normally zero) overflow partials
            __half2 h = *(const __half2*)(num + d);
            float2 f = __half22float2(h);
            float S0 = s0[t] + f.x;
            float S1 = s1[t] + f.y;
            float c0 = bias[0], c1 = bias[1];
            if (D > 0.f) { float inv = 1.0f / D; c0 += S0 * inv; c1 += S1 * inv; }
            float tt = x[d] * fmaxf(c0, 0.f) + fmaxf(c1, 0.f);
            g[d] = 1.0f / (1.0f + __expf(-tt));
        }
    }
}

// ---------------- Fallback kernels (old path, used only if ws too small) -------
__global__ void k_edge(const int* __restrict__ src,
                       const int* __restrict__ dst,
                       const float4* __restrict__ nodeinfo,
                       const float* __restrict__ er_arr,
                       const unsigned* __restrict__ M_enc,
                       unsigned* __restrict__ num,
                       float* __restrict__ denom,
                       int e)
{
    int i = blockIdx.x * blockDim.x + threadIdx.x;
    if (i >= e) return;
    float Mel = dec_f32(*M_enc);
    int s = src[i], d = dst[i];
    float4 ns = nodeinfo[s];
    float erd = er_arr[d];
    float ex = __expf(leaky(ns.x + erd) - leaky(Mel + erd));
    __half2 h = __floats2half2_rn(ex * ns.z, ex * ns.w);
    unsigned hv = *(unsigned*)&h;
    unsigned* np = num + d;
    asm volatile("global_atomic_pk_add_f16 %0, %1, off"
                 :: "v"(np), "v"(hv) : "memory");
    float* dp = denom + d;
    asm volatile("global_atomic_add_f32 %0, %1, off"
                 :: "v"(dp), "v"(ex) : "memory");
}

__global__ void k_reduce(const unsigned* __restrict__ num,
                         const float* __restrict__ denom,
                         const float* __restrict__ x,
                         const float* __restrict__ bias,
                         float* __restrict__ g,
                         int n)
{
    int i = blockIdx.x * blockDim.x + threadIdx.x;
    if (i >= n) return;
    float D = denom[i];
    float c0 = bias[0], c1 = bias[1];
    if (D > 0.0f) {
        __half2 h = *(const __half2*)(num + i);
        float2 f = __half22float2(h);
        float inv = 1.0f / D;
        c0 += f.x * inv;
        c1 += f.y * inv;
    }
    float t = x[i] * fmaxf(c0, 0.0f) + fmaxf(c1, 0.0f);
    g[i] = 1.0f / (1.0f + __expf(-t));
}

// ---------------- Kernel 5: out = input * g[node] ------------------------------
__global__ void k_final(const float* __restrict__ input,
                        const float* __restrict__ g,
                        float* __restrict__ out,
                        int n)
{
    int node = blockIdx.x * 4 + (threadIdx.x >> 6);
    int lane = threadIdx.x & 63;
    if (node >= n) return;
    float gg = g[node];
    const float4* inrow = (const float4*)(input + (size_t)node * HDIM);
    float4* outrow = (float4*)(out + (size_t)node * HDIM);
    float4 v = inrow[lane];
    outrow[lane] = make_float4(v.x * gg, v.y * gg, v.z * gg, v.w * gg);
}

extern "C" void kernel_launch(void* const* d_in, const int* in_sizes, int n_in,
                              void* d_out, int out_size, void* d_ws, size_t ws_size,
                              hipStream_t stream)
{
    const float* input  = (const float*)d_in[0];  // [N,256]
    const float* x      = (const float*)d_in[1];  // [N,1]
    // d_in[2] = degree (unused)
    const int* esrc     = (const int*)d_in[3];    // [E]
    const int* edst     = (const int*)d_in[4];    // [E]
    const float* W      = (const float*)d_in[5];  // [256,2]
    const float* attn_l = (const float*)d_in[6];  // [2]
    const float* attn_r = (const float*)d_in[7];  // [2]
    const float* bias   = (const float*)d_in[8];  // [2]
    float* out = (float*)d_out;

    const int n = in_sizes[1];      // 100000
    const int e = in_sizes[3];      // 3200000

    // ws layout (bytes):
    //   num[4n] | denom[4n] | M_enc[4] pad-to-64 | cursor[4*MAXBKT] |
    //   nodeinfo[16n] | el[4n] | er[4n] | g[4n] | edgebuf[4*nbkt*cap]
    char* ws = (char*)d_ws;
    unsigned* num      = (unsigned*)ws;                               // 4n
    float*    denom    = (float*)(ws + (size_t)4 * n);                // 4n
    unsigned* M_enc    = (unsigned*)(ws + (size_t)8 * n);             // 4 (+60 pad)
    unsigned* cursor   = (unsigned*)(ws + (size_t)8 * n + 64);        // 4*MAXBKT
    size_t    base2    = (size_t)8 * n + 64 + 4 * MAXBKT;             // 16B-aligned (n even)
    float4*   nodeinfo = (float4*)(ws + base2);                       // 16n
    float*    el_arr   = (float*)(ws + base2 + (size_t)16 * n);       // 4n
    float*    er_arr   = (float*)(ws + base2 + (size_t)20 * n);       // 4n
    float*    g        = (float*)(ws + base2 + (size_t)24 * n);       // 4n
    unsigned* edgebuf  = (unsigned*)(ws + base2 + (size_t)28 * n);    // 4*nbkt*cap

    const int nbkt  = (n + BMASK) >> BSHIFT;        // 782
    const int meanb = (nbkt > 0) ? e / nbkt : 0;    // ~4092
    int cap = meanb + meanb / 4 + 64;               // mean + 25% + 64 (>> mean+8sigma)
    cap = (cap + 3) & ~3;                           // x4 so bucket base is 16B aligned
    const size_t need_fast = base2 + (size_t)28 * n + 4ull * nbkt * cap;
    const bool fast = (nbkt <= MAXBKT) && (ws_size >= need_fast);

    // zero num, denom, M_enc, cursor in one shot (ws re-poisoned before every launch)
    hipMemsetAsync(ws, 0, (size_t)8 * n + 64 + 4 * MAXBKT, stream);

    dim3 blk(256);
    int nodeBlocks = (n + 3) / 4;
    int flatBlocks = (n + 255) / 256;

    k_node<<<nodeBlocks, blk, 0, stream>>>(input, W, attn_l, attn_r,
                                           nodeinfo, el_arr, er_arr, n);
    k_maxel<<<120, blk, 0, stream>>>(el_arr, M_enc, n);

    if (fast) {
        int binBlocks = (e + EPB - 1) / EPB;
        k_bin<<<binBlocks, blk, 0, stream>>>(esrc, edst, cursor, edgebuf,
                                             nodeinfo, er_arr, M_enc, num, denom,
                                             e, nbkt, cap);
        k_proc<<<nbkt, blk, 0, stream>>>(cursor, edgebuf, nodeinfo, er_arr, M_enc,
                                         num, denom, x, bias, g, n, cap);
    } else {
        int edgeBlocks = (e + 255) / 256;
        k_edge<<<edgeBlocks, blk, 0, stream>>>(esrc, edst, nodeinfo, er_arr, M_enc,
                                               num, denom, e);
        k_reduce<<<flatBlocks, blk, 0, stream>>>(num, denom, x, bias, g, n);
    }

    k_final<<<nodeBlocks, blk, 0, stream>>>(input, g, out, n);
}

// Round 5
// 339.199 us; speedup vs baseline: 1.0179x; 1.0179x over previous
//
#include <hip/hip_runtime.h>
#include <hip/hip_fp16.h>
#include <math.h>

// Problem constants (from reference): N=100000, H=256, E=3200000, OUT=2
#define HDIM 256
#define NEG_SLOPE 0.2f

// R8: k_proc invariant at ~70us across scalar/ILP8/phase-split loops =>
// issue-side MLP is not the limit. Rate = 13 cy per divergent lane-gather
// ~= small per-CU L1 MSHR pool (every gather misses the 32KB L1; each miss
// holds an MSHR for the ~200cy L2 round trip). Fix: bypass L1 entirely —
// inline-asm global_load_dwordx4 with sc0 (device-coherent, skips TCP),
// 4 gathers/thread batched, explicit vmcnt drain + sched_barrier (rule #18).

#define BSHIFT 7
#define BMASK 127
#define MAXBKT 1024   // supports n <= 131072
#define EPB 6144      // edges per k_bin block (multiple of 1024)

typedef float f32x4 __attribute__((ext_vector_type(4)));

__device__ __forceinline__ float leaky(float v) {
    return v >= 0.0f ? v : NEG_SLOPE * v;
}

// order-preserving float<->uint encoding for atomicMax over signed floats
__device__ __forceinline__ unsigned enc_f32(float f) {
    unsigned b = __float_as_uint(f);
    return b ^ ((b >> 31) ? 0xFFFFFFFFu : 0x80000000u);
}
__device__ __forceinline__ float dec_f32(unsigned u) {
    u ^= ((u >> 31) ? 0x80000000u : 0xFFFFFFFFu);
    return __uint_as_float(u);
}

// ---------------- Kernel 1: per-node z, el, er --------------------------------
__global__ void k_node(const float* __restrict__ input,
                       const float* __restrict__ W,
                       const float* __restrict__ attn_l,
                       const float* __restrict__ attn_r,
                       float4* __restrict__ nodeinfo,  // (el, er, z0, z1)
                       float* __restrict__ el_arr,
                       float* __restrict__ er_arr,
                       int n)
{
    int node = blockIdx.x * 4 + (threadIdx.x >> 6);
    int lane = threadIdx.x & 63;
    if (node >= n) return;

    const float4* inrow = (const float4*)(input + (size_t)node * HDIM);
    float4 v = inrow[lane];
    const float4* Wv = (const float4*)W;
    float4 w0 = Wv[2 * lane];
    float4 w1 = Wv[2 * lane + 1];
    float s0 = v.x * w0.x + v.y * w0.z + v.z * w1.x + v.w * w1.z;
    float s1 = v.x * w0.y + v.y * w0.w + v.z * w1.y + v.w * w1.w;

    #pragma unroll
    for (int off = 32; off > 0; off >>= 1) {
        s0 += __shfl_xor(s0, off);
        s1 += __shfl_xor(s1, off);
    }

    if (lane == 0) {
        float el = s0 * attn_l[0] + s1 * attn_l[1];
        float er = s0 * attn_r[0] + s1 * attn_r[1];
        nodeinfo[node] = make_float4(el, er, s0, s1);
        el_arr[node] = el;
        er_arr[node] = er;
    }
}

// ---------------- Kernel 2: global max of el ----------------------------------
__global__ void k_maxel(const float* __restrict__ el, unsigned* __restrict__ M_enc, int n)
{
    float m = -1e30f;
    for (int i = blockIdx.x * blockDim.x + threadIdx.x; i < n;
         i += gridDim.x * blockDim.x)
        m = fmaxf(m, el[i]);
    #pragma unroll
    for (int off = 32; off > 0; off >>= 1)
        m = fmaxf(m, __shfl_xor(m, off));
    __shared__ float s[4];
    int lane = threadIdx.x & 63, w = threadIdx.x >> 6;
    if (lane == 0) s[w] = m;
    __syncthreads();
    if (threadIdx.x == 0) {
        float mm = fmaxf(fmaxf(s[0], s[1]), fmaxf(s[2], s[3]));
        atomicMax(M_enc, enc_f32(mm));   // M_enc pre-zeroed; enc(0)=0 acts as -inf
    }
}

// ---------------- Kernel 3a: bin edges by dst bucket ---------------------------
// Record: (src << 7) | (dst & 127) fits u32 for n <= 131072.
__global__ __launch_bounds__(256, 4)
void k_bin(const int* __restrict__ src,
           const int* __restrict__ dst,
           unsigned* __restrict__ cursor,    // [nbkt], pre-zeroed
           unsigned* __restrict__ edgebuf,   // [nbkt*cap]
           const float4* __restrict__ nodeinfo,
           const float* __restrict__ er_arr,
           const unsigned* __restrict__ M_enc,
           unsigned* __restrict__ num,       // overflow fallback (pre-zeroed)
           float* __restrict__ denom,        // overflow fallback (pre-zeroed)
           int e, int nbkt, int cap)
{
    __shared__ unsigned h1[MAXBKT];        // counts -> block's base per bucket
    __shared__ unsigned h2[MAXBKT];        // local ranks
    __shared__ unsigned recs[EPB];         // packed records
    __shared__ unsigned short bkt[EPB];    // bucket id per record

    for (int t = threadIdx.x; t < nbkt; t += blockDim.x) { h1[t] = 0u; h2[t] = 0u; }
    __syncthreads();

    int lo = blockIdx.x * EPB;
    int cnt = min(EPB, e - lo);

    // pass 1: coalesced load, pack record, LDS histogram
    if (cnt == EPB) {
        const int4* s4 = (const int4*)(src + lo);
        const int4* d4 = (const int4*)(dst + lo);
        #pragma unroll
        for (int k = 0; k < EPB / 1024; ++k) {
            int i4 = (int)threadIdx.x + k * 256;
            int4 sv = s4[i4];
            int4 dv = d4[i4];
            int i = 4 * i4;
            recs[i + 0] = ((unsigned)sv.x << BSHIFT) | ((unsigned)dv.x & BMASK);
            recs[i + 1] = ((unsigned)sv.y << BSHIFT) | ((unsigned)dv.y & BMASK);
            recs[i + 2] = ((unsigned)sv.z << BSHIFT) | ((unsigned)dv.z & BMASK);
            recs[i + 3] = ((unsigned)sv.w << BSHIFT) | ((unsigned)dv.w & BMASK);
            bkt[i + 0] = (unsigned short)((unsigned)dv.x >> BSHIFT);
            bkt[i + 1] = (unsigned short)((unsigned)dv.y >> BSHIFT);
            bkt[i + 2] = (unsigned short)((unsigned)dv.z >> BSHIFT);
            bkt[i + 3] = (unsigned short)((unsigned)dv.w >> BSHIFT);
            atomicAdd(&h1[(unsigned)dv.x >> BSHIFT], 1u);
            atomicAdd(&h1[(unsigned)dv.y >> BSHIFT], 1u);
            atomicAdd(&h1[(unsigned)dv.z >> BSHIFT], 1u);
            atomicAdd(&h1[(unsigned)dv.w >> BSHIFT], 1u);
        }
    } else {
        for (int i = threadIdx.x; i < cnt; i += blockDim.x) {
            int s = src[lo + i];
            int d = dst[lo + i];
            recs[i] = ((unsigned)s << BSHIFT) | ((unsigned)d & BMASK);
            bkt[i] = (unsigned short)((unsigned)d >> BSHIFT);
            atomicAdd(&h1[(unsigned)d >> BSHIFT], 1u);
        }
    }
    __syncthreads();

    // reserve contiguous per-bucket ranges (the only global atomics)
    for (int t = threadIdx.x; t < nbkt; t += blockDim.x) {
        unsigned c = h1[t];
        h1[t] = c ? atomicAdd(&cursor[t], c) : 0u;
    }
    __syncthreads();

    // pass 2: scatter packed records from LDS
    for (int i = threadIdx.x; i < cnt; i += blockDim.x) {
        int b = (int)bkt[i];
        unsigned rec = recs[i];
        unsigned r = h1[b] + atomicAdd(&h2[b], 1u);
        if (r < (unsigned)cap) {
            edgebuf[(size_t)b * cap + r] = rec;
        } else {
            // statistically-never overflow: old direct global-atomic path
            int s = (int)(rec >> BSHIFT);
            int d = (b << BSHIFT) | (int)(rec & BMASK);
            float Mel = dec_f32(*M_enc);
            float4 ns = nodeinfo[s];
            float erd = er_arr[d];
            float ex = __expf(leaky(ns.x + erd) - leaky(Mel + erd));
            __half2 h = __floats2half2_rn(ex * ns.z, ex * ns.w);
            unsigned hv = *(unsigned*)&h;
            unsigned* np = num + d;
            asm volatile("global_atomic_pk_add_f16 %0, %1, off"
                         :: "v"(np), "v"(hv) : "memory");
            float* dp = denom + d;
            asm volatile("global_atomic_add_f32 %0, %1, off"
                         :: "v"(dp), "v"(ex) : "memory");
        }
    }
}

// ---------------- Kernel 3b: per-bucket LDS accumulate + fused gate ------------
// nodeinfo gathers issued as sc0 (L1-bypass) asm loads, 4/thread, then one
// vmcnt drain + sched_barrier before consumption (guide rule #18).
__global__ __launch_bounds__(256, 4)
void k_proc(const unsigned* __restrict__ cursor,
            const unsigned* __restrict__ edgebuf,
            const float4* __restrict__ nodeinfo,
            const float* __restrict__ er_arr,
            const unsigned* __restrict__ M_enc,
            const unsigned* __restrict__ num,    // overflow partials
            const float* __restrict__ denom,     // overflow partials
            const float* __restrict__ x,
            const float* __restrict__ bias,
            float* __restrict__ g,
            int n, int cap)
{
    __shared__ float sD[128], s0[128], s1[128], ser[128];
    int b = blockIdx.x;
    int dbase = b << BSHIFT;
    int t = threadIdx.x;
    if (t < 128) {
        sD[t] = 0.f; s0[t] = 0.f; s1[t] = 0.f;
        int d = dbase + t;
        ser[t] = (d < n) ? er_arr[d] : 0.f;
    }
    __syncthreads();

    float Mel = dec_f32(*M_enc);
    unsigned cnt = cursor[b];
    if (cnt > (unsigned)cap) cnt = (unsigned)cap;
    const unsigned* buf = edgebuf + (size_t)b * cap;   // 16B aligned (cap % 4 == 0)
    const uint4* buf4 = (const uint4*)buf;
    const f32x4* ni = (const f32x4*)nodeinfo;
    unsigned nvec = cnt >> 2;

    #define PROC1(rec, ns) do {                                        \
        int dl_ = (int)((rec) & BMASK);                                \
        float erd_ = ser[dl_];                                         \
        float ex_ = __expf(leaky((ns).x + erd_) - leaky(Mel + erd_));  \
        atomicAdd(&sD[dl_], ex_);                                      \
        atomicAdd(&s0[dl_], ex_ * (ns).z);                             \
        atomicAdd(&s1[dl_], ex_ * (ns).w);                             \
    } while (0)

    unsigned rounds = (nvec + 255u) >> 8;
    for (unsigned rr = 0; rr < rounds; ++rr) {
        unsigned i4 = (rr << 8) + (unsigned)t;
        bool valid = i4 < nvec;
        uint4 rec4 = valid ? buf4[i4] : make_uint4(0u, 0u, 0u, 0u);
        f32x4 n0, n1, n2, n3;
        // sc0 => bypass L1 (device-coherent load) — avoid the TCP MSHR wall
        asm volatile("global_load_dwordx4 %0, %1, off sc0"
                     : "=v"(n0) : "v"(ni + (rec4.x >> BSHIFT)));
        asm volatile("global_load_dwordx4 %0, %1, off sc0"
                     : "=v"(n1) : "v"(ni + (rec4.y >> BSHIFT)));
        asm volatile("global_load_dwordx4 %0, %1, off sc0"
                     : "=v"(n2) : "v"(ni + (rec4.z >> BSHIFT)));
        asm volatile("global_load_dwordx4 %0, %1, off sc0"
                     : "=v"(n3) : "v"(ni + (rec4.w >> BSHIFT)));
        asm volatile("s_waitcnt vmcnt(0)" ::: "memory");
        __builtin_amdgcn_sched_barrier(0);
        if (valid) {
            PROC1(rec4.x, n0); PROC1(rec4.y, n1);
            PROC1(rec4.z, n2); PROC1(rec4.w, n3);
        }
    }
    // tail: < 4 records
    for (unsigned i = (nvec << 2) + (unsigned)t; i < cnt; i += blockDim.x) {
        unsigned rec = buf[i];
        f32x4 ns;
        asm volatile("global_load_dwordx4 %0, %1, off sc0"
                     : "=v"(ns) : "v"(ni + (rec >> BSHIFT)));
        asm volatile("s_waitcnt vmcnt(0)" ::: "memory");
        __builtin_amdgcn_sched_barrier(0);
        PROC1(rec, ns);
    }
    #undef PROC1
    __syncthreads();

    if (t < 128) {
        int d = dbase + t;
        if (d < n) {
            float D = sD[t] + denom[d];   // merge (normally zero) overflow partials
            __half2 h = *(const __half2*)(num + d);
            float2 f = __half22float2(h);
            float S0 = s0[t] + f.x;
            float S1 = s1[t] + f.y;
            float c0 = bias[0], c1 = bias[1];
            if (D > 0.f) { float inv = 1.0f / D; c0 += S0 * inv; c1 += S1 * inv; }
            float tt = x[d] * fmaxf(c0, 0.f) + fmaxf(c1, 0.f);
            g[d] = 1.0f / (1.0f + __expf(-tt));
        }
    }
}

// ---------------- Fallback kernels (old path, used only if ws too small) -------
__global__ void k_edge(const int* __restrict__ src,
                       const int* __restrict__ dst,
                       const float4* __restrict__ nodeinfo,
                       const float* __restrict__ er_arr,
                       const unsigned* __restrict__ M_enc,
                       unsigned* __restrict__ num,
                       float* __restrict__ denom,
                       int e)
{
    int i = blockIdx.x * blockDim.x + threadIdx.x;
    if (i >= e) return;
    float Mel = dec_f32(*M_enc);
    int s = src[i], d = dst[i];
    float4 ns = nodeinfo[s];
    float erd = er_arr[d];
    float ex = __expf(leaky(ns.x + erd) - leaky(Mel + erd));
    __half2 h = __floats2half2_rn(ex * ns.z, ex * ns.w);
    unsigned hv = *(unsigned*)&h;
    unsigned* np = num + d;
    asm volatile("global_atomic_pk_add_f16 %0, %1, off"
                 :: "v"(np), "v"(hv) : "memory");
    float* dp = denom + d;
    asm volatile("global_atomic_add_f32 %0, %1, off"
                 :: "v"(dp), "v"(ex) : "memory");
}

__global__ void k_reduce(const unsigned* __restrict__ num,
                         const float* __restrict__ denom,
                         const float* __restrict__ x,
                         const float* __restrict__ bias,
                         float* __restrict__ g,
                         int n)
{
    int i = blockIdx.x * blockDim.x + threadIdx.x;
    if (i >= n) return;
    float D = denom[i];
    float c0 = bias[0], c1 = bias[1];
    if (D > 0.0f) {
        __half2 h = *(const __half2*)(num + i);
        float2 f = __half22float2(h);
        float inv = 1.0f / D;
        c0 += f.x * inv;
        c1 += f.y * inv;
    }
    float t = x[i] * fmaxf(c0, 0.0f) + fmaxf(c1, 0.0f);
    g[i] = 1.0f / (1.0f + __expf(-t));
}

// ---------------- Kernel 5: out = input * g[node] ------------------------------
__global__ void k_final(const float* __restrict__ input,
                        const float* __restrict__ g,
                        float* __restrict__ out,
                        int n)
{
    int node = blockIdx.x * 4 + (threadIdx.x >> 6);
    int lane = threadIdx.x & 63;
    if (node >= n) return;
    float gg = g[node];
    const float4* inrow = (const float4*)(input + (size_t)node * HDIM);
    float4* outrow = (float4*)(out + (size_t)node * HDIM);
    float4 v = inrow[lane];
    outrow[lane] = make_float4(v.x * gg, v.y * gg, v.z * gg, v.w * gg);
}

extern "C" void kernel_launch(void* const* d_in, const int* in_sizes, int n_in,
                              void* d_out, int out_size, void* d_ws, size_t ws_size,
                              hipStream_t stream)
{
    const float* input  = (const float*)d_in[0];  // [N,256]
    const float* x      = (const float*)d_in[1];  // [N,1]
    // d_in[2] = degree (unused)
    const int* esrc     = (const int*)d_in[3];    // [E]
    const int* edst     = (const int*)d_in[4];    // [E]
    const float* W      = (const float*)d_in[5];  // [256,2]
    const float* attn_l = (const float*)d_in[6];  // [2]
    const float* attn_r = (const float*)d_in[7];  // [2]
    const float* bias   = (const float*)d_in[8];  // [2]
    float* out = (float*)d_out;

    const int n = in_sizes[1];      // 100000
    const int e = in_sizes[3];      // 3200000

    // ws layout (bytes):
    //   num[4n] | denom[4n] | M_enc[4] pad-to-64 | cursor[4*MAXBKT] |
    //   nodeinfo[16n] | el[4n] | er[4n] | g[4n] | edgebuf[4*nbkt*cap]
    char* ws = (char*)d_ws;
    unsigned* num      = (unsigned*)ws;                               // 4n
    float*    denom    = (float*)(ws + (size_t)4 * n);                // 4n
    unsigned* M_enc    = (unsigned*)(ws + (size_t)8 * n);             // 4 (+60 pad)
    unsigned* cursor   = (unsigned*)(ws + (size_t)8 * n + 64);        // 4*MAXBKT
    size_t    base2    = (size_t)8 * n + 64 + 4 * MAXBKT;             // 16B-aligned (n even)
    float4*   nodeinfo = (float4*)(ws + base2);                       // 16n
    float*    el_arr   = (float*)(ws + base2 + (size_t)16 * n);       // 4n
    float*    er_arr   = (float*)(ws + base2 + (size_t)20 * n);       // 4n
    float*    g        = (float*)(ws + base2 + (size_t)24 * n);       // 4n
    unsigned* edgebuf  = (unsigned*)(ws + base2 + (size_t)28 * n);    // 4*nbkt*cap

    const int nbkt  = (n + BMASK) >> BSHIFT;        // 782
    const int meanb = (nbkt > 0) ? e / nbkt : 0;    // ~4092
    int cap = meanb + meanb / 4 + 64;               // mean + 25% + 64 (>> mean+8sigma)
    cap = (cap + 3) & ~3;                           // x4 so bucket base is 16B aligned
    const size_t need_fast = base2 + (size_t)28 * n + 4ull * nbkt * cap;
    const bool fast = (nbkt <= MAXBKT) && (ws_size >= need_fast);

    // zero num, denom, M_enc, cursor in one shot (ws re-poisoned before every launch)
    hipMemsetAsync(ws, 0, (size_t)8 * n + 64 + 4 * MAXBKT, stream);

    dim3 blk(256);
    int nodeBlocks = (n + 3) / 4;
    int flatBlocks = (n + 255) / 256;

    k_node<<<nodeBlocks, blk, 0, stream>>>(input, W, attn_l, attn_r,
                                           nodeinfo, el_arr, er_arr, n);
    k_maxel<<<120, blk, 0, stream>>>(el_arr, M_enc, n);

    if (fast) {
        int binBlocks = (e + EPB - 1) / EPB;
        k_bin<<<binBlocks, blk, 0, stream>>>(esrc, edst, cursor, edgebuf,
                                             nodeinfo, er_arr, M_enc, num, denom,
                                             e, nbkt, cap);
        k_proc<<<nbkt, blk, 0, stream>>>(cursor, edgebuf, nodeinfo, er_arr, M_enc,
                                         num, denom, x, bias, g, n, cap);
    } else {
        int edgeBlocks = (e + 255) / 256;
        k_edge<<<edgeBlocks, blk, 0, stream>>>(esrc, edst, nodeinfo, er_arr, M_enc,
                                               num, denom, e);
        k_reduce<<<flatBlocks, blk, 0, stream>>>(num, denom, x, bias, g, n);
    }

    k_final<<<nodeBlocks, blk, 0, stream>>>(input, g, out, n);
}

// Round 6
// 328.582 us; speedup vs baseline: 1.0507x; 1.0323x over previous
//
#include <hip/hip_runtime.h>
#include <hip/hip_fp16.h>
#include <math.h>

// Problem constants (from reference): N=100000, H=256, E=3200000, OUT=2
#define HDIM 256
#define NEG_SLOPE 0.2f

// R9: three inner-loop theories (ILP8, phase-split, sc0 L1-bypass) all null;
// k_proc pinned at 70us. Counter re-read: Occupancy 22% = 1.75 waves/SIMD —
// every L3/L2 latency is exposed raw; per-wave serial chain x ~12 wave
// generations/CU ~= measured 168k cy. Fix concurrency, not ILP:
//   k_proc: 1024 thr/block (16 waves) -> 8 waves/SIMD steady state.
//   k_bin : 512 thr/block -> 24 waves/CU.

#define BSHIFT 7
#define BMASK 127
#define MAXBKT 1024     // supports n <= 131072
#define EPB 6144        // edges per k_bin block (multiple of 4*BINTHREADS)
#define BINTHREADS 512
#define PROCTHREADS 1024

__device__ __forceinline__ float leaky(float v) {
    return v >= 0.0f ? v : NEG_SLOPE * v;
}

// order-preserving float<->uint encoding for atomicMax over signed floats
__device__ __forceinline__ unsigned enc_f32(float f) {
    unsigned b = __float_as_uint(f);
    return b ^ ((b >> 31) ? 0xFFFFFFFFu : 0x80000000u);
}
__device__ __forceinline__ float dec_f32(unsigned u) {
    u ^= ((u >> 31) ? 0x80000000u : 0xFFFFFFFFu);
    return __uint_as_float(u);
}

// ---------------- Kernel 1: per-node z, el, er --------------------------------
__global__ void k_node(const float* __restrict__ input,
                       const float* __restrict__ W,
                       const float* __restrict__ attn_l,
                       const float* __restrict__ attn_r,
                       float4* __restrict__ nodeinfo,  // (el, er, z0, z1)
                       float* __restrict__ el_arr,
                       float* __restrict__ er_arr,
                       int n)
{
    int node = blockIdx.x * 4 + (threadIdx.x >> 6);
    int lane = threadIdx.x & 63;
    if (node >= n) return;

    const float4* inrow = (const float4*)(input + (size_t)node * HDIM);
    float4 v = inrow[lane];
    const float4* Wv = (const float4*)W;
    float4 w0 = Wv[2 * lane];
    float4 w1 = Wv[2 * lane + 1];
    float s0 = v.x * w0.x + v.y * w0.z + v.z * w1.x + v.w * w1.z;
    float s1 = v.x * w0.y + v.y * w0.w + v.z * w1.y + v.w * w1.w;

    #pragma unroll
    for (int off = 32; off > 0; off >>= 1) {
        s0 += __shfl_xor(s0, off);
        s1 += __shfl_xor(s1, off);
    }

    if (lane == 0) {
        float el = s0 * attn_l[0] + s1 * attn_l[1];
        float er = s0 * attn_r[0] + s1 * attn_r[1];
        nodeinfo[node] = make_float4(el, er, s0, s1);
        el_arr[node] = el;
        er_arr[node] = er;
    }
}

// ---------------- Kernel 2: global max of el ----------------------------------
__global__ void k_maxel(const float* __restrict__ el, unsigned* __restrict__ M_enc, int n)
{
    float m = -1e30f;
    for (int i = blockIdx.x * blockDim.x + threadIdx.x; i < n;
         i += gridDim.x * blockDim.x)
        m = fmaxf(m, el[i]);
    #pragma unroll
    for (int off = 32; off > 0; off >>= 1)
        m = fmaxf(m, __shfl_xor(m, off));
    __shared__ float s[4];
    int lane = threadIdx.x & 63, w = threadIdx.x >> 6;
    if (lane == 0) s[w] = m;
    __syncthreads();
    if (threadIdx.x == 0) {
        float mm = fmaxf(fmaxf(s[0], s[1]), fmaxf(s[2], s[3]));
        atomicMax(M_enc, enc_f32(mm));   // M_enc pre-zeroed; enc(0)=0 acts as -inf
    }
}

// ---------------- Kernel 3a: bin edges by dst bucket ---------------------------
// Record: (src << 7) | (dst & 127) fits u32 for n <= 131072.
__global__ __launch_bounds__(BINTHREADS)
void k_bin(const int* __restrict__ src,
           const int* __restrict__ dst,
           unsigned* __restrict__ cursor,    // [nbkt], pre-zeroed
           unsigned* __restrict__ edgebuf,   // [nbkt*cap]
           const float4* __restrict__ nodeinfo,
           const float* __restrict__ er_arr,
           const unsigned* __restrict__ M_enc,
           unsigned* __restrict__ num,       // overflow fallback (pre-zeroed)
           float* __restrict__ denom,        // overflow fallback (pre-zeroed)
           int e, int nbkt, int cap)
{
    __shared__ unsigned h1[MAXBKT];        // counts -> block's base per bucket
    __shared__ unsigned h2[MAXBKT];        // local ranks
    __shared__ unsigned recs[EPB];         // packed records
    __shared__ unsigned short bkt[EPB];    // bucket id per record

    for (int t = threadIdx.x; t < nbkt; t += blockDim.x) { h1[t] = 0u; h2[t] = 0u; }
    __syncthreads();

    int lo = blockIdx.x * EPB;
    int cnt = min(EPB, e - lo);

    // pass 1: coalesced load, pack record, LDS histogram
    if (cnt == EPB) {
        const int4* s4 = (const int4*)(src + lo);
        const int4* d4 = (const int4*)(dst + lo);
        #pragma unroll
        for (int k = 0; k < EPB / (4 * BINTHREADS); ++k) {
            int i4 = (int)threadIdx.x + k * BINTHREADS;
            int4 sv = s4[i4];
            int4 dv = d4[i4];
            int i = 4 * i4;
            recs[i + 0] = ((unsigned)sv.x << BSHIFT) | ((unsigned)dv.x & BMASK);
            recs[i + 1] = ((unsigned)sv.y << BSHIFT) | ((unsigned)dv.y & BMASK);
            recs[i + 2] = ((unsigned)sv.z << BSHIFT) | ((unsigned)dv.z & BMASK);
            recs[i + 3] = ((unsigned)sv.w << BSHIFT) | ((unsigned)dv.w & BMASK);
            bkt[i + 0] = (unsigned short)((unsigned)dv.x >> BSHIFT);
            bkt[i + 1] = (unsigned short)((unsigned)dv.y >> BSHIFT);
            bkt[i + 2] = (unsigned short)((unsigned)dv.z >> BSHIFT);
            bkt[i + 3] = (unsigned short)((unsigned)dv.w >> BSHIFT);
            atomicAdd(&h1[(unsigned)dv.x >> BSHIFT], 1u);
            atomicAdd(&h1[(unsigned)dv.y >> BSHIFT], 1u);
            atomicAdd(&h1[(unsigned)dv.z >> BSHIFT], 1u);
            atomicAdd(&h1[(unsigned)dv.w >> BSHIFT], 1u);
        }
    } else {
        for (int i = threadIdx.x; i < cnt; i += blockDim.x) {
            int s = src[lo + i];
            int d = dst[lo + i];
            recs[i] = ((unsigned)s << BSHIFT) | ((unsigned)d & BMASK);
            bkt[i] = (unsigned short)((unsigned)d >> BSHIFT);
            atomicAdd(&h1[(unsigned)d >> BSHIFT], 1u);
        }
    }
    __syncthreads();

    // reserve contiguous per-bucket ranges (the only global atomics)
    for (int t = threadIdx.x; t < nbkt; t += blockDim.x) {
        unsigned c = h1[t];
        h1[t] = c ? atomicAdd(&cursor[t], c) : 0u;
    }
    __syncthreads();

    // pass 2: scatter packed records from LDS
    for (int i = threadIdx.x; i < cnt; i += blockDim.x) {
        int b = (int)bkt[i];
        unsigned rec = recs[i];
        unsigned r = h1[b] + atomicAdd(&h2[b], 1u);
        if (r < (unsigned)cap) {
            edgebuf[(size_t)b * cap + r] = rec;
        } else {
            // statistically-never overflow: old direct global-atomic path
            int s = (int)(rec >> BSHIFT);
            int d = (b << BSHIFT) | (int)(rec & BMASK);
            float Mel = dec_f32(*M_enc);
            float4 ns = nodeinfo[s];
            float erd = er_arr[d];
            float ex = __expf(leaky(ns.x + erd) - leaky(Mel + erd));
            __half2 h = __floats2half2_rn(ex * ns.z, ex * ns.w);
            unsigned hv = *(unsigned*)&h;
            unsigned* np = num + d;
            asm volatile("global_atomic_pk_add_f16 %0, %1, off"
                         :: "v"(np), "v"(hv) : "memory");
            float* dp = denom + d;
            asm volatile("global_atomic_add_f32 %0, %1, off"
                         :: "v"(dp), "v"(ex) : "memory");
        }
    }
}

// ---------------- Kernel 3b: per-bucket LDS accumulate + fused gate ------------
// 1024 threads/block: each thread owns ~4 records (1 uint4), 16 waves/block
// for latency hiding; epilogue on t<128.
__global__ __launch_bounds__(PROCTHREADS)
void k_proc(const unsigned* __restrict__ cursor,
            const unsigned* __restrict__ edgebuf,
            const float4* __restrict__ nodeinfo,
            const float* __restrict__ er_arr,
            const unsigned* __restrict__ M_enc,
            const unsigned* __restrict__ num,    // overflow partials
            const float* __restrict__ denom,     // overflow partials
            const float* __restrict__ x,
            const float* __restrict__ bias,
            float* __restrict__ g,
            int n, int cap)
{
    __shared__ float sD[128], s0[128], s1[128], ser[128];
    int b = blockIdx.x;
    int dbase = b << BSHIFT;
    int t = threadIdx.x;
    if (t < 128) {
        sD[t] = 0.f; s0[t] = 0.f; s1[t] = 0.f;
        int d = dbase + t;
        ser[t] = (d < n) ? er_arr[d] : 0.f;
    }
    __syncthreads();

    float Mel = dec_f32(*M_enc);
    unsigned cnt = cursor[b];
    if (cnt > (unsigned)cap) cnt = (unsigned)cap;
    const unsigned* buf = edgebuf + (size_t)b * cap;   // 16B aligned (cap % 4 == 0)
    const uint4* buf4 = (const uint4*)buf;
    unsigned nvec = cnt >> 2;

    #define PROC1(rec, ns) do {                                        \
        int dl_ = (int)((rec) & BMASK);                                \
        float erd_ = ser[dl_];                                         \
        float ex_ = __expf(leaky((ns).x + erd_) - leaky(Mel + erd_));  \
        atomicAdd(&sD[dl_], ex_);                                      \
        atomicAdd(&s0[dl_], ex_ * (ns).z);                             \
        atomicAdd(&s1[dl_], ex_ * (ns).w);                             \
    } while (0)

    for (unsigned i4 = (unsigned)t; i4 < nvec; i4 += blockDim.x) {
        uint4 ra = buf4[i4];
        float4 na0 = nodeinfo[ra.x >> BSHIFT];
        float4 na1 = nodeinfo[ra.y >> BSHIFT];
        float4 na2 = nodeinfo[ra.z >> BSHIFT];
        float4 na3 = nodeinfo[ra.w >> BSHIFT];
        PROC1(ra.x, na0); PROC1(ra.y, na1); PROC1(ra.z, na2); PROC1(ra.w, na3);
    }
    // tail: < 4 records
    for (unsigned i = (nvec << 2) + (unsigned)t; i < cnt; i += blockDim.x) {
        unsigned rec = buf[i];
        float4 ns = nodeinfo[rec >> BSHIFT];
        PROC1(rec, ns);
    }
    #undef PROC1
    __syncthreads();

    if (t < 128) {
        int d = dbase + t;
        if (d < n) {
            float D = sD[t] + denom[d];   // merge (normally zero) overflow partials
            __half2 h = *(const __half2*)(num + d);
            float2 f = __half22float2(h);
            float S0 = s0[t] + f.x;
            float S1 = s1[t] + f.y;
            float c0 = bias[0], c1 = bias[1];
            if (D > 0.f) { float inv = 1.0f / D; c0 += S0 * inv; c1 += S1 * inv; }
            float tt = x[d] * fmaxf(c0, 0.f) + fmaxf(c1, 0.f);
            g[d] = 1.0f / (1.0f + __expf(-tt));
        }
    }
}

// ---------------- Fallback kernels (old path, used only if ws too small) -------
__global__ void k_edge(const int* __restrict__ src,
                       const int* __restrict__ dst,
                       const float4* __restrict__ nodeinfo,
                       const float* __restrict__ er_arr,
                       const unsigned* __restrict__ M_enc,
                       unsigned* __restrict__ num,
                       float* __restrict__ denom,
                       int e)
{
    int i = blockIdx.x * blockDim.x + threadIdx.x;
    if (i >= e) return;
    float Mel = dec_f32(*M_enc);
    int s = src[i], d = dst[i];
    float4 ns = nodeinfo[s];
    float erd = er_arr[d];
    float ex = __expf(leaky(ns.x + erd) - leaky(Mel + erd));
    __half2 h = __floats2half2_rn(ex * ns.z, ex * ns.w);
    unsigned hv = *(unsigned*)&h;
    unsigned* np = num + d;
    asm volatile("global_atomic_pk_add_f16 %0, %1, off"
                 :: "v"(np), "v"(hv) : "memory");
    float* dp = denom + d;
    asm volatile("global_atomic_add_f32 %0, %1, off"
                 :: "v"(dp), "v"(ex) : "memory");
}

__global__ void k_reduce(const unsigned* __restrict__ num,
                         const float* __restrict__ denom,
                         const float* __restrict__ x,
                         const float* __restrict__ bias,
                         float* __restrict__ g,
                         int n)
{
    int i = blockIdx.x * blockDim.x + threadIdx.x;
    if (i >= n) return;
    float D = denom[i];
    float c0 = bias[0], c1 = bias[1];
    if (D > 0.0f) {
        __half2 h = *(const __half2*)(num + i);
        float2 f = __half22float2(h);
        float inv = 1.0f / D;
        c0 += f.x * inv;
        c1 += f.y * inv;
    }
    float t = x[i] * fmaxf(c0, 0.0f) + fmaxf(c1, 0.0f);
    g[i] = 1.0f / (1.0f + __expf(-t));
}

// ---------------- Kernel 5: out = input * g[node] ------------------------------
__global__ void k_final(const float* __restrict__ input,
                        const float* __restrict__ g,
                        float* __restrict__ out,
                        int n)
{
    int node = blockIdx.x * 4 + (threadIdx.x >> 6);
    int lane = threadIdx.x & 63;
    if (node >= n) return;
    float gg = g[node];
    const float4* inrow = (const float4*)(input + (size_t)node * HDIM);
    float4* outrow = (float4*)(out + (size_t)node * HDIM);
    float4 v = inrow[lane];
    outrow[lane] = make_float4(v.x * gg, v.y * gg, v.z * gg, v.w * gg);
}

extern "C" void kernel_launch(void* const* d_in, const int* in_sizes, int n_in,
                              void* d_out, int out_size, void* d_ws, size_t ws_size,
                              hipStream_t stream)
{
    const float* input  = (const float*)d_in[0];  // [N,256]
    const float* x      = (const float*)d_in[1];  // [N,1]
    // d_in[2] = degree (unused)
    const int* esrc     = (const int*)d_in[3];    // [E]
    const int* edst     = (const int*)d_in[4];    // [E]
    const float* W      = (const float*)d_in[5];  // [256,2]
    const float* attn_l = (const float*)d_in[6];  // [2]
    const float* attn_r = (const float*)d_in[7];  // [2]
    const float* bias   = (const float*)d_in[8];  // [2]
    float* out = (float*)d_out;

    const int n = in_sizes[1];      // 100000
    const int e = in_sizes[3];      // 3200000

    // ws layout (bytes):
    //   num[4n] | denom[4n] | M_enc[4] pad-to-64 | cursor[4*MAXBKT] |
    //   nodeinfo[16n] | el[4n] | er[4n] | g[4n] | edgebuf[4*nbkt*cap]
    char* ws = (char*)d_ws;
    unsigned* num      = (unsigned*)ws;                               // 4n
    float*    denom    = (float*)(ws + (size_t)4 * n);                // 4n
    unsigned* M_enc    = (unsigned*)(ws + (size_t)8 * n);             // 4 (+60 pad)
    unsigned* cursor   = (unsigned*)(ws + (size_t)8 * n + 64);        // 4*MAXBKT
    size_t    base2    = (size_t)8 * n + 64 + 4 * MAXBKT;             // 16B-aligned (n even)
    float4*   nodeinfo = (float4*)(ws + base2);                       // 16n
    float*    el_arr   = (float*)(ws + base2 + (size_t)16 * n);       // 4n
    float*    er_arr   = (float*)(ws + base2 + (size_t)20 * n);       // 4n
    float*    g        = (float*)(ws + base2 + (size_t)24 * n);       // 4n
    unsigned* edgebuf  = (unsigned*)(ws + base2 + (size_t)28 * n);    // 4*nbkt*cap

    const int nbkt  = (n + BMASK) >> BSHIFT;        // 782
    const int meanb = (nbkt > 0) ? e / nbkt : 0;    // ~4092
    int cap = meanb + meanb / 4 + 64;               // mean + 25% + 64 (>> mean+8sigma)
    cap = (cap + 3) & ~3;                           // x4 so bucket base is 16B aligned
    const size_t need_fast = base2 + (size_t)28 * n + 4ull * nbkt * cap;
    const bool fast = (nbkt <= MAXBKT) && (ws_size >= need_fast);

    // zero num, denom, M_enc, cursor in one shot (ws re-poisoned before every launch)
    hipMemsetAsync(ws, 0, (size_t)8 * n + 64 + 4 * MAXBKT, stream);

    dim3 blk(256);
    int nodeBlocks = (n + 3) / 4;
    int flatBlocks = (n + 255) / 256;

    k_node<<<nodeBlocks, blk, 0, stream>>>(input, W, attn_l, attn_r,
                                           nodeinfo, el_arr, er_arr, n);
    k_maxel<<<120, blk, 0, stream>>>(el_arr, M_enc, n);

    if (fast) {
        int binBlocks = (e + EPB - 1) / EPB;
        k_bin<<<binBlocks, dim3(BINTHREADS), 0, stream>>>(
            esrc, edst, cursor, edgebuf, nodeinfo, er_arr, M_enc, num, denom,
            e, nbkt, cap);
        k_proc<<<nbkt, dim3(PROCTHREADS), 0, stream>>>(
            cursor, edgebuf, nodeinfo, er_arr, M_enc,
            num, denom, x, bias, g, n, cap);
    } else {
        int edgeBlocks = (e + 255) / 256;
        k_edge<<<edgeBlocks, blk, 0, stream>>>(esrc, edst, nodeinfo, er_arr, M_enc,
                                               num, denom, e);
        k_reduce<<<flatBlocks, blk, 0, stream>>>(num, denom, x, bias, g, n);
    }

    k_final<<<nodeBlocks, blk, 0, stream>>>(input, g, out, n);
}